// Round 9
// baseline (175.742 us; speedup 1.0000x reference)
//
#include <hip/hip_runtime.h>

typedef __bf16 bf16;
typedef __attribute__((ext_vector_type(8))) __bf16 bf16x8;
typedef __attribute__((ext_vector_type(4))) float f32x4;
typedef __attribute__((ext_vector_type(4))) unsigned int u32x4;

#define DINC 256
#define HIDC 512
#define XLRW 768   // xlry row width: [xl(256) | xr(256) | y(256)]

__device__ __forceinline__ float lrelu02(float v) { return fmaxf(v, 0.2f * v); }

__device__ __forceinline__ void gload_lds16(const void* g, void* l) {
    __builtin_amdgcn_global_load_lds(
        (const __attribute__((address_space(1))) unsigned int*)g,
        (__attribute__((address_space(3))) unsigned int*)l, 16, 0, 0);
}

// ---------------------------------------------------------------------------
// 128x128 tile bf16 MFMA GEMM body (round-2 verified structure), BK=32.
// 256 thr = 4 waves, wave owns 64x64 (4x4 16x16 frags). A:[M][K], Bt:[N][K].
// ---------------------------------------------------------------------------
__device__ __forceinline__ void gemm128_body(
    const bf16* __restrict__ A, const bf16* __restrict__ Bt,
    const float* __restrict__ bias, void* __restrict__ Cout,
    int K, int ldc, int col_off, int bx, int by, int relu, int outbf16,
    bf16* As, bf16* Bs)   // each 128*32 elements (8 KB)
{
    const int t = threadIdx.x;
    const int w = t >> 6, lane = t & 63;
    const long brow = (long)by * 128;
    const long bcol = (long)bx * 128;
    const int wr = (w >> 1) * 64, wc = (w & 1) * 64;
    const int fr = lane & 15, half = lane >> 4;
    const int srow = lane >> 2;
    const int skof = (lane & 3) * 8;

    f32x4 acc[4][4] = {};

    for (int k0 = 0; k0 < K; k0 += 32) {
        __syncthreads();
#pragma unroll
        for (int c2 = 0; c2 < 2; ++c2) {
            const int c = w + c2 * 4;
            const int row = c * 16 + srow;
            gload_lds16(A  + (brow + row) * K + k0 + skof, &As[c * 512]);
            gload_lds16(Bt + (bcol + row) * K + k0 + skof, &Bs[c * 512]);
        }
        __syncthreads();
        bf16x8 af[4], bfr[4];
#pragma unroll
        for (int i = 0; i < 4; ++i)
            af[i] = *(const bf16x8*)&As[(wr + i * 16 + fr) * 32 + half * 8];
#pragma unroll
        for (int j = 0; j < 4; ++j)
            bfr[j] = *(const bf16x8*)&Bs[(wc + j * 16 + fr) * 32 + half * 8];
#pragma unroll
        for (int i = 0; i < 4; ++i)
#pragma unroll
            for (int j = 0; j < 4; ++j)
                acc[i][j] = __builtin_amdgcn_mfma_f32_16x16x32_bf16(
                    af[i], bfr[j], acc[i][j], 0, 0, 0);
    }

#pragma unroll
    for (int i = 0; i < 4; ++i) {
#pragma unroll
        for (int j = 0; j < 4; ++j) {
            const long gcol = bcol + wc + j * 16 + fr;
            const float bv = bias ? bias[gcol] : 0.0f;
#pragma unroll
            for (int v = 0; v < 4; ++v) {
                const long grow = brow + wr + i * 16 + half * 4 + v;
                float val = acc[i][j][v] + bv;
                if (relu) val = fmaxf(val, 0.0f);
                if (outbf16) ((bf16*)Cout)[grow * ldc + col_off + gcol] = (bf16)val;
                else         ((float*)Cout)[grow * ldc + col_off + gcol] = val;
            }
        }
    }
}

template<int RELU, int OUTBF16>
__global__ __launch_bounds__(256) void gemm128(
    const bf16* __restrict__ A, const bf16* __restrict__ Bt,
    const float* __restrict__ bias, void* __restrict__ Cout,
    int K, int ldc, int col_off)
{
    __shared__ bf16 As[128 * 32];
    __shared__ bf16 Bs[128 * 32];
    gemm128_body(A, Bt, bias, Cout, K, ldc, col_off,
                 blockIdx.x, blockIdx.y, RELU, OUTBF16, As, Bs);
}

// ---------------------------------------------------------------------------
// 64x64 tile BK=64 body (for the tiny Wcomb GEMM).
// ---------------------------------------------------------------------------
__device__ __forceinline__ void gemm64_body(
    const bf16* __restrict__ A, const bf16* __restrict__ Bt,
    const float* __restrict__ bias, void* __restrict__ Cout,
    int K, int ldc, int col_off, int bx, int by, int relu, int outbf16,
    bf16* As, bf16* Bs)   // each >= 64*64 elements
{
    const int t = threadIdx.x;
    const int w = t >> 6, lane = t & 63;
    const long brow = (long)by * 64;
    const long bcol = (long)bx * 64;
    const int wr = (w >> 1) * 32, wc = (w & 1) * 32;
    const int fr = lane & 15, half = lane >> 4;
    const int srow = t >> 3;
    const int scol = (t & 7) * 8;

    const bf16* Ag = A  + (brow + srow) * K + scol;
    const bf16* Bg = Bt + (bcol + srow) * K + scol;
    const long rowK32 = (long)32 * K;

    f32x4 acc[2][2] = {};

    for (int k0 = 0; k0 < K; k0 += 64) {
        __syncthreads();
        gload_lds16(Ag + k0,          &As[t * 8]);
        gload_lds16(Ag + k0 + rowK32, &As[2048 + t * 8]);
        gload_lds16(Bg + k0,          &Bs[t * 8]);
        gload_lds16(Bg + k0 + rowK32, &Bs[2048 + t * 8]);
        __syncthreads();
#pragma unroll
        for (int ks = 0; ks < 2; ++ks) {
            bf16x8 af[2], bfr[2];
#pragma unroll
            for (int i = 0; i < 2; ++i)
                af[i] = *(const bf16x8*)&As[(wr + i * 16 + fr) * 64 + ks * 32 + half * 8];
#pragma unroll
            for (int j = 0; j < 2; ++j)
                bfr[j] = *(const bf16x8*)&Bs[(wc + j * 16 + fr) * 64 + ks * 32 + half * 8];
#pragma unroll
            for (int i = 0; i < 2; ++i)
#pragma unroll
                for (int j = 0; j < 2; ++j)
                    acc[i][j] = __builtin_amdgcn_mfma_f32_16x16x32_bf16(
                        af[i], bfr[j], acc[i][j], 0, 0, 0);
        }
    }

#pragma unroll
    for (int i = 0; i < 2; ++i) {
#pragma unroll
        for (int j = 0; j < 2; ++j) {
            const long gcol = bcol + wc + j * 16 + fr;
            const float bv = bias ? bias[gcol] : 0.0f;
#pragma unroll
            for (int v = 0; v < 4; ++v) {
                const long grow = brow + wr + i * 16 + half * 4 + v;
                float val = acc[i][j][v] + bv;
                if (relu) val = fmaxf(val, 0.0f);
                if (outbf16) ((bf16*)Cout)[grow * ldc + col_off + gcol] = (bf16)val;
                else         ((float*)Cout)[grow * ldc + col_off + gcol] = val;
            }
        }
    }
}

// ---------------------------------------------------------------------------
// mega_prep, grid (16,16,8): transposes, converts, fills, bias_comb.
// ---------------------------------------------------------------------------
__global__ __launch_bounds__(256) void mega_prep(
    const float* __restrict__ W_l, const float* __restrict__ W_r,
    const float* __restrict__ gin_W1, const float* __restrict__ fus_W,
    const float* __restrict__ gin_b2, const float* __restrict__ fus_b,
    const float* __restrict__ x, const float* __restrict__ W2,
    bf16* __restrict__ Wlrw_t, bf16* __restrict__ Wfused_t,
    bf16* __restrict__ Wfbot_t, bf16* __restrict__ W2b,
    bf16* __restrict__ xb, float* __restrict__ bias_comb,
    u32x4* __restrict__ cnt, int cnt4, u32x4* __restrict__ bm, int bm4)
{
    const int z = blockIdx.z;
    const int t = threadIdx.x;
    if (z < 5) {
        const float* s; bf16* d; int K, Nc, ldd;
        switch (z) {
            case 0: s = W_l;            d = Wlrw_t;          K = 256; Nc = 256; ldd = 256; break;
            case 1: s = W_r;            d = Wlrw_t + 65536;  K = 256; Nc = 256; ldd = 256; break;
            case 2: s = gin_W1;         d = Wlrw_t + 131072; K = 256; Nc = 256; ldd = 256; break;
            case 3: s = fus_W;          d = Wfused_t;        K = 256; Nc = 512; ldd = 512; break;
            default: s = fus_W + 256 * 512; d = Wfbot_t;     K = 256; Nc = 512; ldd = 256; break;
        }
        const int bn = blockIdx.x * 32, bk = blockIdx.y * 32;
        if (bn >= Nc || bk >= K) return;
        __shared__ float tile[32][33];
        const int tx = t & 31, ty = t >> 5;
#pragma unroll
        for (int r = 0; r < 32; r += 8)
            tile[ty + r][tx] = s[(size_t)(bk + ty + r) * Nc + bn + tx];
        __syncthreads();
#pragma unroll
        for (int r = 0; r < 32; r += 8)
            d[(size_t)(bn + ty + r) * ldd + bk + tx] = (bf16)tile[tx][ty + r];
        return;
    }
    const int bid = blockIdx.y * 16 + blockIdx.x;
    if (z == 5) {
        if (bid >= 32) return;
        const int u = bid * 256 + t;
        const float4* wv = (const float4*)W2;
        float4 a = wv[(size_t)u * 2], b = wv[(size_t)u * 2 + 1];
        bf16x8 o;
        o[0] = (bf16)a.x; o[1] = (bf16)a.y; o[2] = (bf16)a.z; o[3] = (bf16)a.w;
        o[4] = (bf16)b.x; o[5] = (bf16)b.y; o[6] = (bf16)b.z; o[7] = (bf16)b.w;
        *(bf16x8*)&W2b[(size_t)u * 8] = o;
        return;
    }
    if (z == 6) {
        const int u0 = bid * 256 + t;
        const float4* xv = (const float4*)x;
#pragma unroll
        for (int r = 0; r < 4; ++r) {
            const int u = u0 + r * 65536;
            float4 a = xv[(size_t)u * 2], b = xv[(size_t)u * 2 + 1];
            bf16x8 o;
            o[0] = (bf16)a.x; o[1] = (bf16)a.y; o[2] = (bf16)a.z; o[3] = (bf16)a.w;
            o[4] = (bf16)b.x; o[5] = (bf16)b.y; o[6] = (bf16)b.z; o[7] = (bf16)b.w;
            *(bf16x8*)&xb[(size_t)u * 8] = o;
        }
        return;
    }
    // z == 7: bias_comb + zero fills
    const int gid = bid * 256 + t;
    if (gid < 512) {
        float acc = fus_b[gid];
        for (int j = 0; j < 256; ++j)
            acc += gin_b2[j] * fus_W[(size_t)(256 + j) * 512 + gid];
        bias_comb[gid] = acc;
    }
    const int stride = 256 * 256;
    const u32x4 zv = {0u, 0u, 0u, 0u};
    for (int i = gid; i < cnt4; i += stride) cnt[i] = zv;
    for (int i = gid; i < bm4; i += stride) bm[i] = zv;
}

// ---------------------------------------------------------------------------
// CSR build
// ---------------------------------------------------------------------------
__global__ __launch_bounds__(256) void build_hist(
    const int* __restrict__ src, const int* __restrict__ dst, int E, int N,
    int* __restrict__ cnt_dst, int* __restrict__ cnt_src,
    unsigned int* __restrict__ bitmap, unsigned char* __restrict__ flags)
{
    int e = blockIdx.x * 256 + threadIdx.x;
    if (e >= E) return;
    int s = src[e], d = dst[e];
    atomicAdd(&cnt_dst[d], 1);
    unsigned int key  = (unsigned int)s * (unsigned int)N + (unsigned int)d;
    unsigned int word = key >> 5;
    unsigned int bit  = 1u << (key & 31u);
    unsigned int old  = atomicOr(&bitmap[word], bit);
    int own = (old & bit) == 0u;
    flags[e] = (unsigned char)own;
    if (own) atomicAdd(&cnt_src[s], 1);
}

// scan; dst direction reserves slot 0 of each segment for the self-loop and
// writes csr_src[off[d]] = d directly.
__global__ __launch_bounds__(1024) void scan_both(
    const int* __restrict__ cnt_dst, int* __restrict__ off_dst, int* __restrict__ cur_dst,
    const int* __restrict__ cnt_src, int* __restrict__ off_src, int* __restrict__ cur_src,
    int* __restrict__ csr_self)
{
    const int self = (blockIdx.x == 0);
    const int* cnt = self ? cnt_dst : cnt_src;
    int* off = self ? off_dst : off_src;
    int* cur = self ? cur_dst : cur_src;
    __shared__ int lds[1024];
    const int t = threadIdx.x;
    const int base = t * 8;
    int v[8]; int s = 0;
#pragma unroll
    for (int j = 0; j < 8; ++j) { v[j] = cnt[base + j] + self; s += v[j]; }
    lds[t] = s;
    __syncthreads();
    int mine = s;
    for (int o = 1; o < 1024; o <<= 1) {
        int add = (t >= o) ? lds[t - o] : 0;
        __syncthreads();
        lds[t] += add;
        __syncthreads();
    }
    int run = lds[t] - mine;
#pragma unroll
    for (int j = 0; j < 8; ++j) {
        off[base + j] = run;
        cur[base + j] = run + self;
        if (self) csr_self[run] = base + j;
        run += v[j];
    }
    if (t == 1023) off[8192] = run;
}

// ---------------------------------------------------------------------------
// Heterogeneous: scatter | x@[Wl|Wr|W1] GEMM (128^2) | Wcomb GEMM (64^2)
// ---------------------------------------------------------------------------
__global__ __launch_bounds__(256) void scatter_gemms(
    const int* __restrict__ src, const int* __restrict__ dst, int E,
    int* __restrict__ cur_dst, int* __restrict__ cur_src,
    const unsigned char* __restrict__ flags,
    int* __restrict__ csr_src, int* __restrict__ csr_gin,
    const bf16* __restrict__ xb, const bf16* __restrict__ Wlrw_t,
    bf16* __restrict__ xlry,
    const bf16* __restrict__ Wfbot_t, const bf16* __restrict__ W2b,
    bf16* __restrict__ Wfused_t)
{
    __shared__ bf16 As[128 * 32];
    __shared__ bf16 Bs[128 * 32];
    const int nsc = (E + 255) >> 8;
    int bid = blockIdx.x;
    if (bid < nsc) {
        int e = bid * 256 + threadIdx.x;
        if (e >= E) return;
        int s = src[e], d = dst[e];
        int p = atomicAdd(&cur_dst[d], 1);
        csr_src[p] = s;
        if (flags[e]) {
            int q = atomicAdd(&cur_src[s], 1);
            csr_gin[q] = d;
        }
        return;
    }
    bid -= nsc;
    if (bid < 384) {
        // xlry = xb @ [W_l|W_r|W1]: M=8192, N=768, K=256
        gemm128_body(xb, Wlrw_t, nullptr, xlry, 256, XLRW, 0,
                     bid % 6, bid / 6, 0, 1, As, Bs);
        return;
    }
    bid -= 384;
    // Wfused bottom = Wcomb^T: grid 4x8
    gemm64_body(Wfbot_t, W2b, nullptr, Wfused_t, 256, HIDC, 256,
                bid & 3, bid >> 2, 0, 1, As, Bs);
}

// ---------------------------------------------------------------------------
// Merged GAT (blocks 0..N-1) + GIN aggregate (blocks N..2N-1).
// GAT: single-pass online softmax w/ defer-rescale; self-loops pre-inserted
// into CSR so all slots are uniform. GIN: aggregates y = x@W1 and writes
// relu(. + b1) directly into cat[:,256:512].
// ---------------------------------------------------------------------------
__global__ __launch_bounds__(256, 8) void gatgin(
    const bf16* __restrict__ xlry, const int* __restrict__ csr_src,
    const int* __restrict__ off_dst, const float* __restrict__ att,
    const float* __restrict__ b_gat, bf16* __restrict__ cat,
    const int* __restrict__ csr_gin, const int* __restrict__ off_src,
    const float* __restrict__ gin_b1, int N)
{
    __shared__ float red[8 * 256];
    __shared__ float mslot[8][4];
    __shared__ float dslot[8][4];
    const int t = threadIdx.x;
    const int e8 = t >> 5, g = t & 31;

    if (blockIdx.x >= N) {
        // ---------------- GIN aggregate over y (cols 512..767 of xlry) -----
        const int i = blockIdx.x - N;
        const int beg = off_src[i], end = off_src[i + 1];
        const bf16* ybase = xlry + 512 + g * 8;
        float a0 = 0, a1 = 0, a2 = 0, a3 = 0, a4 = 0, a5 = 0, a6 = 0, a7 = 0;
        if (e8 == 0) {
            bf16x8 xv = *(const bf16x8*)(ybase + (size_t)i * XLRW);
            a0 = (float)xv[0]; a1 = (float)xv[1]; a2 = (float)xv[2]; a3 = (float)xv[3];
            a4 = (float)xv[4]; a5 = (float)xv[5]; a6 = (float)xv[6]; a7 = (float)xv[7];
        }
        for (int j = beg + e8; j < end; j += 8) {
            const int s = csr_gin[j];
            bf16x8 v = *(const bf16x8*)(ybase + (size_t)s * XLRW);
            a0 += (float)v[0]; a1 += (float)v[1]; a2 += (float)v[2]; a3 += (float)v[3];
            a4 += (float)v[4]; a5 += (float)v[5]; a6 += (float)v[6]; a7 += (float)v[7];
        }
        f32x4 lo = {a0, a1, a2, a3}, hi = {a4, a5, a6, a7};
        *(f32x4*)&red[e8 * 256 + g * 8]     = lo;
        *(f32x4*)&red[e8 * 256 + g * 8 + 4] = hi;
        __syncthreads();
        float acc = 0.0f;
#pragma unroll
        for (int s = 0; s < 8; ++s) acc += red[s * 256 + t];
        cat[(size_t)i * HIDC + 256 + t] = (bf16)fmaxf(acc + gin_b1[t], 0.0f);
        return;
    }

    // ---------------- GATv2, single-pass online softmax ----------------
    const int d = blockIdx.x;
    const int beg = off_dst[d];
    const int cnt = off_dst[d + 1] - beg;   // includes self slot

    float xr8[8], at8[8];
    {
        bf16x8 xv = *(const bf16x8*)&xlry[(size_t)d * XLRW + 256 + g * 8];
#pragma unroll
        for (int f = 0; f < 8; ++f) xr8[f] = (float)xv[f];
        float4 q0 = *(const float4*)&att[g * 8];
        float4 q1 = *(const float4*)&att[g * 8 + 4];
        at8[0] = q0.x; at8[1] = q0.y; at8[2] = q0.z; at8[3] = q0.w;
        at8[4] = q1.x; at8[5] = q1.y; at8[6] = q1.z; at8[7] = q1.w;
    }

    const bf16* base = xlry + g * 8;
    float m = -1e30f, den = 0.0f;
    float a[8];
#pragma unroll
    for (int f = 0; f < 8; ++f) a[f] = 0.0f;

    for (int jj = e8; jj < cnt; jj += 8) {
        const int s = csr_src[beg + jj];
        bf16x8 v = *(const bf16x8*)(base + (size_t)s * XLRW);
        float vf[8];
        float p = 0.0f;
#pragma unroll
        for (int f = 0; f < 8; ++f) {
            vf[f] = (float)v[f];
            p += lrelu02(vf[f] + xr8[f]) * at8[f];
        }
        p += __shfl_xor(p, 1);
        p += __shfl_xor(p, 2);
        p += __shfl_xor(p, 4);          // p uniform within 8-lane head-group
        if (p > m) {                    // defer-rescale: rare after warmup
            const float r = __expf(m - p);
            den *= r;
#pragma unroll
            for (int f = 0; f < 8; ++f) a[f] *= r;
            m = p;
        }
        const float w = __expf(p - m);
        den += w;
#pragma unroll
        for (int f = 0; f < 8; ++f) a[f] = fmaf(w, vf[f], a[f]);
    }

    {
        f32x4 lo = {a[0], a[1], a[2], a[3]}, hi = {a[4], a[5], a[6], a[7]};
        *(f32x4*)&red[e8 * 256 + g * 8]     = lo;
        *(f32x4*)&red[e8 * 256 + g * 8 + 4] = hi;
        if ((g & 7) == 0) { mslot[e8][g >> 3] = m; dslot[e8][g >> 3] = den; }
    }
    __syncthreads();

    const int h = t >> 6;
    float M = mslot[0][h];
#pragma unroll
    for (int s2 = 1; s2 < 8; ++s2) M = fmaxf(M, mslot[s2][h]);
    float accv = 0.0f, dd = 0.0f;
#pragma unroll
    for (int s2 = 0; s2 < 8; ++s2) {
        const float sc = __expf(mslot[s2][h] - M);   // 0 for empty slots
        accv = fmaf(sc, red[s2 * 256 + t], accv);
        dd   = fmaf(sc, dslot[s2][h], dd);
    }
    cat[(size_t)d * HIDC + t] = (bf16)(accv / dd + b_gat[t]);
}

// LayerNorm over 512 features (bf16 in, fp32 out)
__global__ __launch_bounds__(256) void layernorm512(
    const bf16* __restrict__ cbuf, const float* __restrict__ g,
    const float* __restrict__ b, float* __restrict__ out)
{
    const int r = blockIdx.x;
    const int t = threadIdx.x;
    typedef __attribute__((ext_vector_type(2))) __bf16 bf16x2;
    bf16x2 pv = *(const bf16x2*)&cbuf[(size_t)r * HIDC + t * 2];
    float v0 = (float)pv[0], v1 = (float)pv[1];
    float s = v0 + v1;
    float q = v0 * v0 + v1 * v1;
    for (int o = 1; o < 64; o <<= 1) {
        s += __shfl_xor(s, o);
        q += __shfl_xor(q, o);
    }
    __shared__ float ls[4], lq[4];
    int w = t >> 6;
    if ((t & 63) == 0) { ls[w] = s; lq[w] = q; }
    __syncthreads();
    s = ls[0] + ls[1] + ls[2] + ls[3];
    q = lq[0] + lq[1] + lq[2] + lq[3];
    float mu  = s * (1.0f / 512.0f);
    float var = q * (1.0f / 512.0f) - mu * mu;
    float rs  = rsqrtf(var + 1e-5f);
    int c0 = t * 2;
    out[(size_t)r * HIDC + c0]     = (v0 - mu) * rs * g[c0]     + b[c0];
    out[(size_t)r * HIDC + c0 + 1] = (v1 - mu) * rs * g[c0 + 1] + b[c0 + 1];
}

// ---------------------------------------------------------------------------
extern "C" void kernel_launch(void* const* d_in, const int* in_sizes, int n_in,
                              void* d_out, int out_size, void* d_ws, size_t ws_size,
                              hipStream_t stream)
{
    const float* x      = (const float*)d_in[0];
    const float* W_l    = (const float*)d_in[1];
    const float* W_r    = (const float*)d_in[2];
    const float* att    = (const float*)d_in[3];
    const float* b_gat  = (const float*)d_in[4];
    const float* gin_W1 = (const float*)d_in[5];
    const float* gin_b1 = (const float*)d_in[6];
    const float* gin_W2 = (const float*)d_in[7];
    const float* gin_b2 = (const float*)d_in[8];
    const float* fus_W  = (const float*)d_in[9];
    const float* fus_b  = (const float*)d_in[10];
    const float* ln_g   = (const float*)d_in[11];
    const float* ln_b   = (const float*)d_in[12];
    const int*   eidx   = (const int*)d_in[13];

    const int E = in_sizes[13] / 2;
    const int N = in_sizes[0] / DINC;  // 8192
    const int* src = eidx;
    const int* dst = eidx + E;

    char* ws = (char*)d_ws;
    size_t off = 0;
    auto alloc = [&](size_t bytes) -> void* {
        void* p = ws + off;
        off = (off + bytes + 255) & ~(size_t)255;
        return p;
    };
    bf16* xb       = (bf16*)alloc((size_t)N * DINC * 2);
    bf16* xlry     = (bf16*)alloc((size_t)N * XLRW * 2);
    bf16* Wlrw_t   = (bf16*)alloc((size_t)768 * 256 * 2);
    bf16* Wfused_t = (bf16*)alloc((size_t)512 * 512 * 2);
    bf16* Wfbot_t  = (bf16*)alloc((size_t)512 * 256 * 2);
    bf16* W2b      = (bf16*)alloc((size_t)256 * 256 * 2);
    bf16* cat      = (bf16*)alloc((size_t)N * HIDC * 2);
    bf16* cbuf     = (bf16*)alloc((size_t)N * HIDC * 2);
    float* bias_comb = (float*)alloc(512 * 4);
    int* cnt_dst = (int*)alloc((size_t)N * 4);   // cnt_dst+cnt_src contiguous
    int* cnt_src = (int*)alloc((size_t)N * 4);
    int* off_dst = (int*)alloc((size_t)(N + 1) * 4);
    int* cur_dst = (int*)alloc((size_t)N * 4);
    int* off_src = (int*)alloc((size_t)(N + 1) * 4);
    int* cur_src = (int*)alloc((size_t)N * 4);
    int* csr_src = (int*)alloc((size_t)(E + N) * 4);   // edges + self slots
    int* csr_gin = (int*)alloc((size_t)E * 4);
    unsigned char* flags  = (unsigned char*)alloc((size_t)E);
    unsigned int*  bitmap = (unsigned int*)alloc((size_t)N * (size_t)N / 8);

    mega_prep<<<dim3(16, 16, 8), 256, 0, stream>>>(
        W_l, W_r, gin_W1, fus_W, gin_b2, fus_b, x, gin_W2,
        Wlrw_t, Wfused_t, Wfbot_t, W2b, xb, bias_comb,
        (u32x4*)cnt_dst, (2 * N) / 4,
        (u32x4*)bitmap, (int)((size_t)N * N / 32 / 4));

    build_hist<<<(E + 255) / 256, 256, 0, stream>>>(src, dst, E, N, cnt_dst, cnt_src, bitmap, flags);
    scan_both<<<2, 1024, 0, stream>>>(cnt_dst, off_dst, cur_dst,
                                      cnt_src, off_src, cur_src, csr_src);

    const int nsc = (E + 255) / 256;
    scatter_gemms<<<nsc + 384 + 32, 256, 0, stream>>>(
        src, dst, E, cur_dst, cur_src, flags, csr_src, csr_gin,
        xb, Wlrw_t, xlry, Wfbot_t, W2b, Wfused_t);

    gatgin<<<2 * N, 256, 0, stream>>>(xlry, csr_src, off_dst, att, b_gat, cat,
                                      csr_gin, off_src, gin_b1, N);

    // fusion: relu(cat @ Wfused + bias_comb) -> cbuf (128^2 MFMA)
    gemm128<1, 1><<<dim3(4, 64), 256, 0, stream>>>(cat, Wfused_t, bias_comb, cbuf, 512, HIDC, 0);
    layernorm512<<<N, 256, 0, stream>>>(cbuf, ln_g, ln_b, (float*)d_out);

    (void)n_in; (void)out_size; (void)ws_size;
}

// Round 10
// 167.756 us; speedup vs baseline: 1.0476x; 1.0476x over previous
//
#include <hip/hip_runtime.h>

typedef __bf16 bf16;
typedef __attribute__((ext_vector_type(8))) __bf16 bf16x8;
typedef __attribute__((ext_vector_type(4))) float f32x4;
typedef __attribute__((ext_vector_type(4))) unsigned int u32x4;

#define DINC 256
#define HIDC 512
#define XLRW 768   // xlry row width: [xl(256) | xr(256) | y(256)]

__device__ __forceinline__ float lrelu02(float v) { return fmaxf(v, 0.2f * v); }

__device__ __forceinline__ void gload_lds16(const void* g, void* l) {
    __builtin_amdgcn_global_load_lds(
        (const __attribute__((address_space(1))) unsigned int*)g,
        (__attribute__((address_space(3))) unsigned int*)l, 16, 0, 0);
}

// ---------------------------------------------------------------------------
// 64x64 tile BK=64 bf16 MFMA GEMM body (round-5 proven best for these shapes).
// ---------------------------------------------------------------------------
__device__ __forceinline__ void gemm64_body(
    const bf16* __restrict__ A, const bf16* __restrict__ Bt,
    const float* __restrict__ bias, void* __restrict__ Cout,
    int K, int ldc, int col_off, int bx, int by, int relu, int outbf16,
    bf16* As, bf16* Bs)   // each 64*64 elements (8 KB)
{
    const int t = threadIdx.x;
    const int w = t >> 6, lane = t & 63;
    const long brow = (long)by * 64;
    const long bcol = (long)bx * 64;
    const int wr = (w >> 1) * 32, wc = (w & 1) * 32;
    const int fr = lane & 15, half = lane >> 4;
    const int srow = t >> 3;
    const int scol = (t & 7) * 8;

    const bf16* Ag = A  + (brow + srow) * K + scol;
    const bf16* Bg = Bt + (bcol + srow) * K + scol;
    const long rowK32 = (long)32 * K;

    f32x4 acc[2][2] = {};

    for (int k0 = 0; k0 < K; k0 += 64) {
        __syncthreads();
        gload_lds16(Ag + k0,          &As[t * 8]);
        gload_lds16(Ag + k0 + rowK32, &As[2048 + t * 8]);
        gload_lds16(Bg + k0,          &Bs[t * 8]);
        gload_lds16(Bg + k0 + rowK32, &Bs[2048 + t * 8]);
        __syncthreads();
#pragma unroll
        for (int ks = 0; ks < 2; ++ks) {
            bf16x8 af[2], bfr[2];
#pragma unroll
            for (int i = 0; i < 2; ++i)
                af[i] = *(const bf16x8*)&As[(wr + i * 16 + fr) * 64 + ks * 32 + half * 8];
#pragma unroll
            for (int j = 0; j < 2; ++j)
                bfr[j] = *(const bf16x8*)&Bs[(wc + j * 16 + fr) * 64 + ks * 32 + half * 8];
#pragma unroll
            for (int i = 0; i < 2; ++i)
#pragma unroll
                for (int j = 0; j < 2; ++j)
                    acc[i][j] = __builtin_amdgcn_mfma_f32_16x16x32_bf16(
                        af[i], bfr[j], acc[i][j], 0, 0, 0);
        }
    }

#pragma unroll
    for (int i = 0; i < 2; ++i) {
#pragma unroll
        for (int j = 0; j < 2; ++j) {
            const long gcol = bcol + wc + j * 16 + fr;
            const float bv = bias ? bias[gcol] : 0.0f;
#pragma unroll
            for (int v = 0; v < 4; ++v) {
                const long grow = brow + wr + i * 16 + half * 4 + v;
                float val = acc[i][j][v] + bv;
                if (relu) val = fmaxf(val, 0.0f);
                if (outbf16) ((bf16*)Cout)[grow * ldc + col_off + gcol] = (bf16)val;
                else         ((float*)Cout)[grow * ldc + col_off + gcol] = val;
            }
        }
    }
}

template<int RELU, int OUTBF16>
__global__ __launch_bounds__(256) void gemm64(
    const bf16* __restrict__ A, const bf16* __restrict__ Bt,
    const float* __restrict__ bias, void* __restrict__ Cout,
    int K, int ldc, int col_off)
{
    __shared__ bf16 As[64 * 64];
    __shared__ bf16 Bs[64 * 64];
    gemm64_body(A, Bt, bias, Cout, K, ldc, col_off,
                blockIdx.x, blockIdx.y, RELU, OUTBF16, As, Bs);
}

// ---------------------------------------------------------------------------
// mega_prep, grid (16,16,8): transposes, converts, fills, bias_comb.
// ---------------------------------------------------------------------------
__global__ __launch_bounds__(256) void mega_prep(
    const float* __restrict__ W_l, const float* __restrict__ W_r,
    const float* __restrict__ gin_W1, const float* __restrict__ fus_W,
    const float* __restrict__ gin_b2, const float* __restrict__ fus_b,
    const float* __restrict__ x, const float* __restrict__ W2,
    bf16* __restrict__ Wlrw_t, bf16* __restrict__ Wfused_t,
    bf16* __restrict__ Wfbot_t, bf16* __restrict__ W2b,
    bf16* __restrict__ xb, float* __restrict__ bias_comb,
    u32x4* __restrict__ cnt, int cnt4, u32x4* __restrict__ bm, int bm4)
{
    const int z = blockIdx.z;
    const int t = threadIdx.x;
    if (z < 5) {
        const float* s; bf16* d; int K, Nc, ldd;
        switch (z) {
            case 0: s = W_l;            d = Wlrw_t;          K = 256; Nc = 256; ldd = 256; break;
            case 1: s = W_r;            d = Wlrw_t + 65536;  K = 256; Nc = 256; ldd = 256; break;
            case 2: s = gin_W1;         d = Wlrw_t + 131072; K = 256; Nc = 256; ldd = 256; break;
            case 3: s = fus_W;          d = Wfused_t;        K = 256; Nc = 512; ldd = 512; break;
            default: s = fus_W + 256 * 512; d = Wfbot_t;     K = 256; Nc = 512; ldd = 256; break;
        }
        const int bn = blockIdx.x * 32, bk = blockIdx.y * 32;
        if (bn >= Nc || bk >= K) return;
        __shared__ float tile[32][33];
        const int tx = t & 31, ty = t >> 5;
#pragma unroll
        for (int r = 0; r < 32; r += 8)
            tile[ty + r][tx] = s[(size_t)(bk + ty + r) * Nc + bn + tx];
        __syncthreads();
#pragma unroll
        for (int r = 0; r < 32; r += 8)
            d[(size_t)(bn + ty + r) * ldd + bk + tx] = (bf16)tile[tx][ty + r];
        return;
    }
    const int bid = blockIdx.y * 16 + blockIdx.x;
    if (z == 5) {
        if (bid >= 32) return;
        const int u = bid * 256 + t;
        const float4* wv = (const float4*)W2;
        float4 a = wv[(size_t)u * 2], b = wv[(size_t)u * 2 + 1];
        bf16x8 o;
        o[0] = (bf16)a.x; o[1] = (bf16)a.y; o[2] = (bf16)a.z; o[3] = (bf16)a.w;
        o[4] = (bf16)b.x; o[5] = (bf16)b.y; o[6] = (bf16)b.z; o[7] = (bf16)b.w;
        *(bf16x8*)&W2b[(size_t)u * 8] = o;
        return;
    }
    if (z == 6) {
        const int u0 = bid * 256 + t;
        const float4* xv = (const float4*)x;
#pragma unroll
        for (int r = 0; r < 4; ++r) {
            const int u = u0 + r * 65536;
            float4 a = xv[(size_t)u * 2], b = xv[(size_t)u * 2 + 1];
            bf16x8 o;
            o[0] = (bf16)a.x; o[1] = (bf16)a.y; o[2] = (bf16)a.z; o[3] = (bf16)a.w;
            o[4] = (bf16)b.x; o[5] = (bf16)b.y; o[6] = (bf16)b.z; o[7] = (bf16)b.w;
            *(bf16x8*)&xb[(size_t)u * 8] = o;
        }
        return;
    }
    // z == 7: bias_comb + zero fills
    const int gid = bid * 256 + t;
    if (gid < 512) {
        float acc = fus_b[gid];
        for (int j = 0; j < 256; ++j)
            acc += gin_b2[j] * fus_W[(size_t)(256 + j) * 512 + gid];
        bias_comb[gid] = acc;
    }
    const int stride = 256 * 256;
    const u32x4 zv = {0u, 0u, 0u, 0u};
    for (int i = gid; i < cnt4; i += stride) cnt[i] = zv;
    for (int i = gid; i < bm4; i += stride) bm[i] = zv;
}

// ---------------------------------------------------------------------------
// CSR build
// ---------------------------------------------------------------------------
__global__ __launch_bounds__(256) void build_hist(
    const int* __restrict__ src, const int* __restrict__ dst, int E, int N,
    int* __restrict__ cnt_dst, int* __restrict__ cnt_src,
    unsigned int* __restrict__ bitmap, unsigned char* __restrict__ flags)
{
    int e = blockIdx.x * 256 + threadIdx.x;
    if (e >= E) return;
    int s = src[e], d = dst[e];
    atomicAdd(&cnt_dst[d], 1);
    unsigned int key  = (unsigned int)s * (unsigned int)N + (unsigned int)d;
    unsigned int word = key >> 5;
    unsigned int bit  = 1u << (key & 31u);
    unsigned int old  = atomicOr(&bitmap[word], bit);
    int own = (old & bit) == 0u;
    flags[e] = (unsigned char)own;
    if (own) atomicAdd(&cnt_src[s], 1);
}

// scan; dst direction reserves slot 0 per segment for the self-loop and
// writes csr_src[off[d]] = d directly.
__global__ __launch_bounds__(1024) void scan_both(
    const int* __restrict__ cnt_dst, int* __restrict__ off_dst, int* __restrict__ cur_dst,
    const int* __restrict__ cnt_src, int* __restrict__ off_src, int* __restrict__ cur_src,
    int* __restrict__ csr_self)
{
    const int self = (blockIdx.x == 0);
    const int* cnt = self ? cnt_dst : cnt_src;
    int* off = self ? off_dst : off_src;
    int* cur = self ? cur_dst : cur_src;
    __shared__ int lds[1024];
    const int t = threadIdx.x;
    const int base = t * 8;
    int v[8]; int s = 0;
#pragma unroll
    for (int j = 0; j < 8; ++j) { v[j] = cnt[base + j] + self; s += v[j]; }
    lds[t] = s;
    __syncthreads();
    int mine = s;
    for (int o = 1; o < 1024; o <<= 1) {
        int add = (t >= o) ? lds[t - o] : 0;
        __syncthreads();
        lds[t] += add;
        __syncthreads();
    }
    int run = lds[t] - mine;
#pragma unroll
    for (int j = 0; j < 8; ++j) {
        off[base + j] = run;
        cur[base + j] = run + self;
        if (self) csr_self[run] = base + j;
        run += v[j];
    }
    if (t == 1023) off[8192] = run;
}

// ---------------------------------------------------------------------------
// Heterogeneous: scatter (nsc) | x@[Wl|Wr|W1] GEMM (1536, 64^2) | Wcomb (32)
// ---------------------------------------------------------------------------
__global__ __launch_bounds__(256) void scatter_gemms(
    const int* __restrict__ src, const int* __restrict__ dst, int E,
    int* __restrict__ cur_dst, int* __restrict__ cur_src,
    const unsigned char* __restrict__ flags,
    int* __restrict__ csr_src, int* __restrict__ csr_gin,
    const bf16* __restrict__ xb, const bf16* __restrict__ Wlrw_t,
    bf16* __restrict__ xlry,
    const bf16* __restrict__ Wfbot_t, const bf16* __restrict__ W2b,
    bf16* __restrict__ Wfused_t)
{
    __shared__ bf16 As[64 * 64];
    __shared__ bf16 Bs[64 * 64];
    const int nsc = (E + 255) >> 8;
    int bid = blockIdx.x;
    if (bid < nsc) {
        int e = bid * 256 + threadIdx.x;
        if (e >= E) return;
        int s = src[e], d = dst[e];
        int p = atomicAdd(&cur_dst[d], 1);
        csr_src[p] = s;
        if (flags[e]) {
            int q = atomicAdd(&cur_src[s], 1);
            csr_gin[q] = d;
        }
        return;
    }
    bid -= nsc;
    if (bid < 1536) {
        // xlry = xb @ [W_l|W_r|W1]: M=8192, N=768, K=256; grid 12 x 128
        gemm64_body(xb, Wlrw_t, nullptr, xlry, 256, XLRW, 0,
                    bid % 12, bid / 12, 0, 1, As, Bs);
        return;
    }
    bid -= 1536;
    // Wfused bottom = Wcomb^T: grid 4x8
    gemm64_body(Wfbot_t, W2b, nullptr, Wfused_t, 256, HIDC, 256,
                bid & 3, bid >> 2, 0, 1, As, Bs);
}

// ---------------------------------------------------------------------------
// Merged GAT (blocks 0..N-1) + GIN aggregate (blocks N..2N-1).
// GAT: single-pass online softmax, 2-chunk software pipeline (2 gathers in
// flight per thread). Self-loops pre-inserted into CSR.
// GIN: aggregates y = x@W1, writes relu(. + b1) into cat[:,256:512].
// ---------------------------------------------------------------------------
__global__ __launch_bounds__(256, 8) void gatgin(
    const bf16* __restrict__ xlry, const int* __restrict__ csr_src,
    const int* __restrict__ off_dst, const float* __restrict__ att,
    const float* __restrict__ b_gat, bf16* __restrict__ cat,
    const int* __restrict__ csr_gin, const int* __restrict__ off_src,
    const float* __restrict__ gin_b1, int N)
{
    __shared__ float red[8 * 256];
    __shared__ float mslot[8][4];
    __shared__ float dslot[8][4];
    const int t = threadIdx.x;
    const int e8 = t >> 5, g = t & 31;

    if (blockIdx.x >= N) {
        // ---------------- GIN aggregate over y (cols 512..767), unroll x2 --
        const int i = blockIdx.x - N;
        const int beg = off_src[i], end = off_src[i + 1];
        const bf16* ybase = xlry + 512 + g * 8;
        float a0 = 0, a1 = 0, a2 = 0, a3 = 0, a4 = 0, a5 = 0, a6 = 0, a7 = 0;
        if (e8 == 0) {
            bf16x8 xv = *(const bf16x8*)(ybase + (size_t)i * XLRW);
            a0 = (float)xv[0]; a1 = (float)xv[1]; a2 = (float)xv[2]; a3 = (float)xv[3];
            a4 = (float)xv[4]; a5 = (float)xv[5]; a6 = (float)xv[6]; a7 = (float)xv[7];
        }
        int j = beg + e8;
        for (; j + 8 < end; j += 16) {
            const int s0 = csr_gin[j];
            const int s1 = csr_gin[j + 8];
            bf16x8 v0 = *(const bf16x8*)(ybase + (size_t)s0 * XLRW);
            bf16x8 v1 = *(const bf16x8*)(ybase + (size_t)s1 * XLRW);
            a0 += (float)v0[0] + (float)v1[0]; a1 += (float)v0[1] + (float)v1[1];
            a2 += (float)v0[2] + (float)v1[2]; a3 += (float)v0[3] + (float)v1[3];
            a4 += (float)v0[4] + (float)v1[4]; a5 += (float)v0[5] + (float)v1[5];
            a6 += (float)v0[6] + (float)v1[6]; a7 += (float)v0[7] + (float)v1[7];
        }
        if (j < end) {
            const int s = csr_gin[j];
            bf16x8 v = *(const bf16x8*)(ybase + (size_t)s * XLRW);
            a0 += (float)v[0]; a1 += (float)v[1]; a2 += (float)v[2]; a3 += (float)v[3];
            a4 += (float)v[4]; a5 += (float)v[5]; a6 += (float)v[6]; a7 += (float)v[7];
        }
        f32x4 lo = {a0, a1, a2, a3}, hi = {a4, a5, a6, a7};
        *(f32x4*)&red[e8 * 256 + g * 8]     = lo;
        *(f32x4*)&red[e8 * 256 + g * 8 + 4] = hi;
        __syncthreads();
        float acc = 0.0f;
#pragma unroll
        for (int s = 0; s < 8; ++s) acc += red[s * 256 + t];
        cat[(size_t)i * HIDC + 256 + t] = (bf16)fmaxf(acc + gin_b1[t], 0.0f);
        return;
    }

    // ---------------- GATv2, single-pass online softmax, pipelined x2 ------
    const int d = blockIdx.x;
    const int beg = off_dst[d];
    const int cnt = off_dst[d + 1] - beg;   // includes self slot

    float xr8[8], at8[8];
    {
        bf16x8 xv = *(const bf16x8*)&xlry[(size_t)d * XLRW + 256 + g * 8];
#pragma unroll
        for (int f = 0; f < 8; ++f) xr8[f] = (float)xv[f];
        float4 q0 = *(const float4*)&att[g * 8];
        float4 q1 = *(const float4*)&att[g * 8 + 4];
        at8[0] = q0.x; at8[1] = q0.y; at8[2] = q0.z; at8[3] = q0.w;
        at8[4] = q1.x; at8[5] = q1.y; at8[6] = q1.z; at8[7] = q1.w;
    }

    const bf16* base = xlry + g * 8;
    float m = -1e30f, den = 0.0f;
    float a[8];
#pragma unroll
    for (int f = 0; f < 8; ++f) a[f] = 0.0f;

    int jj = e8;
    for (; jj + 8 < cnt; jj += 16) {
        const int s0 = csr_src[beg + jj];
        const int s1 = csr_src[beg + jj + 8];
        bf16x8 v0 = *(const bf16x8*)(base + (size_t)s0 * XLRW);
        bf16x8 v1 = *(const bf16x8*)(base + (size_t)s1 * XLRW);
        float vf0[8], vf1[8];
        float p0 = 0.0f, p1 = 0.0f;
#pragma unroll
        for (int f = 0; f < 8; ++f) {
            vf0[f] = (float)v0[f];
            vf1[f] = (float)v1[f];
            p0 += lrelu02(vf0[f] + xr8[f]) * at8[f];
            p1 += lrelu02(vf1[f] + xr8[f]) * at8[f];
        }
        p0 += __shfl_xor(p0, 1); p1 += __shfl_xor(p1, 1);
        p0 += __shfl_xor(p0, 2); p1 += __shfl_xor(p1, 2);
        p0 += __shfl_xor(p0, 4); p1 += __shfl_xor(p1, 4);
        if (p0 > m) {
            const float r = __expf(m - p0);
            den *= r;
#pragma unroll
            for (int f = 0; f < 8; ++f) a[f] *= r;
            m = p0;
        }
        {
            const float w = __expf(p0 - m);
            den += w;
#pragma unroll
            for (int f = 0; f < 8; ++f) a[f] = fmaf(w, vf0[f], a[f]);
        }
        if (p1 > m) {
            const float r = __expf(m - p1);
            den *= r;
#pragma unroll
            for (int f = 0; f < 8; ++f) a[f] *= r;
            m = p1;
        }
        {
            const float w = __expf(p1 - m);
            den += w;
#pragma unroll
            for (int f = 0; f < 8; ++f) a[f] = fmaf(w, vf1[f], a[f]);
        }
    }
    if (jj < cnt) {
        const int s = csr_src[beg + jj];
        bf16x8 v = *(const bf16x8*)(base + (size_t)s * XLRW);
        float vf[8];
        float p = 0.0f;
#pragma unroll
        for (int f = 0; f < 8; ++f) {
            vf[f] = (float)v[f];
            p += lrelu02(vf[f] + xr8[f]) * at8[f];
        }
        p += __shfl_xor(p, 1);
        p += __shfl_xor(p, 2);
        p += __shfl_xor(p, 4);
        if (p > m) {
            const float r = __expf(m - p);
            den *= r;
#pragma unroll
            for (int f = 0; f < 8; ++f) a[f] *= r;
            m = p;
        }
        const float w = __expf(p - m);
        den += w;
#pragma unroll
        for (int f = 0; f < 8; ++f) a[f] = fmaf(w, vf[f], a[f]);
    }

    {
        f32x4 lo = {a[0], a[1], a[2], a[3]}, hi = {a[4], a[5], a[6], a[7]};
        *(f32x4*)&red[e8 * 256 + g * 8]     = lo;
        *(f32x4*)&red[e8 * 256 + g * 8 + 4] = hi;
        if ((g & 7) == 0) { mslot[e8][g >> 3] = m; dslot[e8][g >> 3] = den; }
    }
    __syncthreads();

    const int h = t >> 6;
    float M = mslot[0][h];
#pragma unroll
    for (int s2 = 1; s2 < 8; ++s2) M = fmaxf(M, mslot[s2][h]);
    float accv = 0.0f, dd = 0.0f;
#pragma unroll
    for (int s2 = 0; s2 < 8; ++s2) {
        const float sc = __expf(mslot[s2][h] - M);   // 0 for empty slots
        accv = fmaf(sc, red[s2 * 256 + t], accv);
        dd   = fmaf(sc, dslot[s2][h], dd);
    }
    cat[(size_t)d * HIDC + t] = (bf16)(accv / dd + b_gat[t]);
}

// LayerNorm over 512 features (bf16 in, fp32 out)
__global__ __launch_bounds__(256) void layernorm512(
    const bf16* __restrict__ cbuf, const float* __restrict__ g,
    const float* __restrict__ b, float* __restrict__ out)
{
    const int r = blockIdx.x;
    const int t = threadIdx.x;
    typedef __attribute__((ext_vector_type(2))) __bf16 bf16x2;
    bf16x2 pv = *(const bf16x2*)&cbuf[(size_t)r * HIDC + t * 2];
    float v0 = (float)pv[0], v1 = (float)pv[1];
    float s = v0 + v1;
    float q = v0 * v0 + v1 * v1;
    for (int o = 1; o < 64; o <<= 1) {
        s += __shfl_xor(s, o);
        q += __shfl_xor(q, o);
    }
    __shared__ float ls[4], lq[4];
    int w = t >> 6;
    if ((t & 63) == 0) { ls[w] = s; lq[w] = q; }
    __syncthreads();
    s = ls[0] + ls[1] + ls[2] + ls[3];
    q = lq[0] + lq[1] + lq[2] + lq[3];
    float mu  = s * (1.0f / 512.0f);
    float var = q * (1.0f / 512.0f) - mu * mu;
    float rs  = rsqrtf(var + 1e-5f);
    int c0 = t * 2;
    out[(size_t)r * HIDC + c0]     = (v0 - mu) * rs * g[c0]     + b[c0];
    out[(size_t)r * HIDC + c0 + 1] = (v1 - mu) * rs * g[c0 + 1] + b[c0 + 1];
}

// ---------------------------------------------------------------------------
extern "C" void kernel_launch(void* const* d_in, const int* in_sizes, int n_in,
                              void* d_out, int out_size, void* d_ws, size_t ws_size,
                              hipStream_t stream)
{
    const float* x      = (const float*)d_in[0];
    const float* W_l    = (const float*)d_in[1];
    const float* W_r    = (const float*)d_in[2];
    const float* att    = (const float*)d_in[3];
    const float* b_gat  = (const float*)d_in[4];
    const float* gin_W1 = (const float*)d_in[5];
    const float* gin_b1 = (const float*)d_in[6];
    const float* gin_W2 = (const float*)d_in[7];
    const float* gin_b2 = (const float*)d_in[8];
    const float* fus_W  = (const float*)d_in[9];
    const float* fus_b  = (const float*)d_in[10];
    const float* ln_g   = (const float*)d_in[11];
    const float* ln_b   = (const float*)d_in[12];
    const int*   eidx   = (const int*)d_in[13];

    const int E = in_sizes[13] / 2;
    const int N = in_sizes[0] / DINC;  // 8192
    const int* src = eidx;
    const int* dst = eidx + E;

    char* ws = (char*)d_ws;
    size_t off = 0;
    auto alloc = [&](size_t bytes) -> void* {
        void* p = ws + off;
        off = (off + bytes + 255) & ~(size_t)255;
        return p;
    };
    bf16* xb       = (bf16*)alloc((size_t)N * DINC * 2);
    bf16* xlry     = (bf16*)alloc((size_t)N * XLRW * 2);
    bf16* Wlrw_t   = (bf16*)alloc((size_t)768 * 256 * 2);
    bf16* Wfused_t = (bf16*)alloc((size_t)512 * 512 * 2);
    bf16* Wfbot_t  = (bf16*)alloc((size_t)512 * 256 * 2);
    bf16* W2b      = (bf16*)alloc((size_t)256 * 256 * 2);
    bf16* cat      = (bf16*)alloc((size_t)N * HIDC * 2);
    bf16* cbuf     = (bf16*)alloc((size_t)N * HIDC * 2);
    float* bias_comb = (float*)alloc(512 * 4);
    int* cnt_dst = (int*)alloc((size_t)N * 4);   // cnt_dst+cnt_src contiguous
    int* cnt_src = (int*)alloc((size_t)N * 4);
    int* off_dst = (int*)alloc((size_t)(N + 1) * 4);
    int* cur_dst = (int*)alloc((size_t)N * 4);
    int* off_src = (int*)alloc((size_t)(N + 1) * 4);
    int* cur_src = (int*)alloc((size_t)N * 4);
    int* csr_src = (int*)alloc((size_t)(E + N) * 4);   // edges + self slots
    int* csr_gin = (int*)alloc((size_t)E * 4);
    unsigned char* flags  = (unsigned char*)alloc((size_t)E);
    unsigned int*  bitmap = (unsigned int*)alloc((size_t)N * (size_t)N / 8);

    mega_prep<<<dim3(16, 16, 8), 256, 0, stream>>>(
        W_l, W_r, gin_W1, fus_W, gin_b2, fus_b, x, gin_W2,
        Wlrw_t, Wfused_t, Wfbot_t, W2b, xb, bias_comb,
        (u32x4*)cnt_dst, (2 * N) / 4,
        (u32x4*)bitmap, (int)((size_t)N * N / 32 / 4));

    build_hist<<<(E + 255) / 256, 256, 0, stream>>>(src, dst, E, N, cnt_dst, cnt_src, bitmap, flags);
    scan_both<<<2, 1024, 0, stream>>>(cnt_dst, off_dst, cur_dst,
                                      cnt_src, off_src, cur_src, csr_src);

    const int nsc = (E + 255) / 256;
    scatter_gemms<<<nsc + 1536 + 32, 256, 0, stream>>>(
        src, dst, E, cur_dst, cur_src, flags, csr_src, csr_gin,
        xb, Wlrw_t, xlry, Wfbot_t, W2b, Wfused_t);

    gatgin<<<2 * N, 256, 0, stream>>>(xlry, csr_src, off_dst, att, b_gat, cat,
                                      csr_gin, off_src, gin_b1, N);

    // fusion: relu(cat @ Wfused + bias_comb) -> cbuf (64^2 MFMA, 1024 blocks)
    gemm64<1, 1><<<dim3(8, 128), 256, 0, stream>>>(cat, Wfused_t, bias_comb, cbuf, 512, HIDC, 0);
    layernorm512<<<N, 256, 0, stream>>>(cbuf, ln_g, ln_b, (float*)d_out);

    (void)n_in; (void)out_size; (void)ws_size;
}

// Round 11
// 166.946 us; speedup vs baseline: 1.0527x; 1.0049x over previous
//
#include <hip/hip_runtime.h>

typedef __bf16 bf16;
typedef __attribute__((ext_vector_type(8))) __bf16 bf16x8;
typedef __attribute__((ext_vector_type(4))) float f32x4;
typedef __attribute__((ext_vector_type(4))) unsigned int u32x4;

#define DINC 256
#define HIDC 512
#define XLRW 768   // xlry row width: [xl(256) | xr(256) | y(256)]

__device__ __forceinline__ float lrelu02(float v) { return fmaxf(v, 0.2f * v); }

__device__ __forceinline__ void gload_lds16(const void* g, void* l) {
    __builtin_amdgcn_global_load_lds(
        (const __attribute__((address_space(1))) unsigned int*)g,
        (__attribute__((address_space(3))) unsigned int*)l, 16, 0, 0);
}

// ---------------------------------------------------------------------------
// 64x64 tile BK=64 bf16 MFMA GEMM body, bank-conflict-free via XOR swizzle:
// LDS dest stays linear (global_load_lds requirement); the per-lane GLOBAL
// source chunk is pre-swizzled by (row&7), and reads XOR the chunk likewise.
// ---------------------------------------------------------------------------
__device__ __forceinline__ void gemm64_body(
    const bf16* __restrict__ A, const bf16* __restrict__ Bt,
    const float* __restrict__ bias, void* __restrict__ Cout,
    int K, int ldc, int col_off, int bx, int by, int relu, int outbf16,
    bf16* As, bf16* Bs)   // each 64*64 elements (8 KB)
{
    const int t = threadIdx.x;
    const int w = t >> 6, lane = t & 63;
    const long brow = (long)by * 64;
    const long bcol = (long)bx * 64;
    const int wr = (w >> 1) * 32, wc = (w & 1) * 32;
    const int fr = lane & 15, half = lane >> 4;
    const int srow = t >> 3;                      // staging row (0..31)
    const int scol = (((t & 7) ^ (srow & 7))) * 8; // swizzled global chunk

    const bf16* Ag = A  + (brow + srow) * K + scol;
    const bf16* Bg = Bt + (bcol + srow) * K + scol;
    const long rowK32 = (long)32 * K;             // (srow+32)&7 == srow&7

    f32x4 acc[2][2] = {};

    for (int k0 = 0; k0 < K; k0 += 64) {
        __syncthreads();
        gload_lds16(Ag + k0,          &As[t * 8]);
        gload_lds16(Ag + k0 + rowK32, &As[2048 + t * 8]);
        gload_lds16(Bg + k0,          &Bs[t * 8]);
        gload_lds16(Bg + k0 + rowK32, &Bs[2048 + t * 8]);
        __syncthreads();
#pragma unroll
        for (int ks = 0; ks < 2; ++ks) {
            // read swizzle: physical chunk = (ks*4 + half) ^ (row&7); row&7 == fr&7
            const int csw = ((ks * 4 + half) ^ (fr & 7)) * 8;
            bf16x8 af[2], bfr[2];
#pragma unroll
            for (int i = 0; i < 2; ++i)
                af[i] = *(const bf16x8*)&As[(wr + i * 16 + fr) * 64 + csw];
#pragma unroll
            for (int j = 0; j < 2; ++j)
                bfr[j] = *(const bf16x8*)&Bs[(wc + j * 16 + fr) * 64 + csw];
#pragma unroll
            for (int i = 0; i < 2; ++i)
#pragma unroll
                for (int j = 0; j < 2; ++j)
                    acc[i][j] = __builtin_amdgcn_mfma_f32_16x16x32_bf16(
                        af[i], bfr[j], acc[i][j], 0, 0, 0);
        }
    }

#pragma unroll
    for (int i = 0; i < 2; ++i) {
#pragma unroll
        for (int j = 0; j < 2; ++j) {
            const long gcol = bcol + wc + j * 16 + fr;
            const float bv = bias ? bias[gcol] : 0.0f;
#pragma unroll
            for (int v = 0; v < 4; ++v) {
                const long grow = brow + wr + i * 16 + half * 4 + v;
                float val = acc[i][j][v] + bv;
                if (relu) val = fmaxf(val, 0.0f);
                if (outbf16) ((bf16*)Cout)[grow * ldc + col_off + gcol] = (bf16)val;
                else         ((float*)Cout)[grow * ldc + col_off + gcol] = val;
            }
        }
    }
}

template<int RELU, int OUTBF16>
__global__ __launch_bounds__(256) void gemm64(
    const bf16* __restrict__ A, const bf16* __restrict__ Bt,
    const float* __restrict__ bias, void* __restrict__ Cout,
    int K, int ldc, int col_off)
{
    __shared__ bf16 As[64 * 64];
    __shared__ bf16 Bs[64 * 64];
    gemm64_body(A, Bt, bias, Cout, K, ldc, col_off,
                blockIdx.x, blockIdx.y, RELU, OUTBF16, As, Bs);
}

// ---------------------------------------------------------------------------
// mega_prep, grid (16,16,8): transposes, converts, fills, bias_comb.
// ---------------------------------------------------------------------------
__global__ __launch_bounds__(256) void mega_prep(
    const float* __restrict__ W_l, const float* __restrict__ W_r,
    const float* __restrict__ gin_W1, const float* __restrict__ fus_W,
    const float* __restrict__ gin_b2, const float* __restrict__ fus_b,
    const float* __restrict__ x, const float* __restrict__ W2,
    bf16* __restrict__ Wlrw_t, bf16* __restrict__ Wfused_t,
    bf16* __restrict__ Wfbot_t, bf16* __restrict__ W2b,
    bf16* __restrict__ xb, float* __restrict__ bias_comb,
    u32x4* __restrict__ cnt, int cnt4, u32x4* __restrict__ bm, int bm4)
{
    const int z = blockIdx.z;
    const int t = threadIdx.x;
    if (z < 5) {
        const float* s; bf16* d; int K, Nc, ldd;
        switch (z) {
            case 0: s = W_l;            d = Wlrw_t;          K = 256; Nc = 256; ldd = 256; break;
            case 1: s = W_r;            d = Wlrw_t + 65536;  K = 256; Nc = 256; ldd = 256; break;
            case 2: s = gin_W1;         d = Wlrw_t + 131072; K = 256; Nc = 256; ldd = 256; break;
            case 3: s = fus_W;          d = Wfused_t;        K = 256; Nc = 512; ldd = 512; break;
            default: s = fus_W + 256 * 512; d = Wfbot_t;     K = 256; Nc = 512; ldd = 256; break;
        }
        const int bn = blockIdx.x * 32, bk = blockIdx.y * 32;
        if (bn >= Nc || bk >= K) return;
        __shared__ float tile[32][33];
        const int tx = t & 31, ty = t >> 5;
#pragma unroll
        for (int r = 0; r < 32; r += 8)
            tile[ty + r][tx] = s[(size_t)(bk + ty + r) * Nc + bn + tx];
        __syncthreads();
#pragma unroll
        for (int r = 0; r < 32; r += 8)
            d[(size_t)(bn + ty + r) * ldd + bk + tx] = (bf16)tile[tx][ty + r];
        return;
    }
    const int bid = blockIdx.y * 16 + blockIdx.x;
    if (z == 5) {
        if (bid >= 32) return;
        const int u = bid * 256 + t;
        const float4* wv = (const float4*)W2;
        float4 a = wv[(size_t)u * 2], b = wv[(size_t)u * 2 + 1];
        bf16x8 o;
        o[0] = (bf16)a.x; o[1] = (bf16)a.y; o[2] = (bf16)a.z; o[3] = (bf16)a.w;
        o[4] = (bf16)b.x; o[5] = (bf16)b.y; o[6] = (bf16)b.z; o[7] = (bf16)b.w;
        *(bf16x8*)&W2b[(size_t)u * 8] = o;
        return;
    }
    if (z == 6) {
        const int u0 = bid * 256 + t;
        const float4* xv = (const float4*)x;
#pragma unroll
        for (int r = 0; r < 4; ++r) {
            const int u = u0 + r * 65536;
            float4 a = xv[(size_t)u * 2], b = xv[(size_t)u * 2 + 1];
            bf16x8 o;
            o[0] = (bf16)a.x; o[1] = (bf16)a.y; o[2] = (bf16)a.z; o[3] = (bf16)a.w;
            o[4] = (bf16)b.x; o[5] = (bf16)b.y; o[6] = (bf16)b.z; o[7] = (bf16)b.w;
            *(bf16x8*)&xb[(size_t)u * 8] = o;
        }
        return;
    }
    // z == 7: bias_comb + zero fills
    const int gid = bid * 256 + t;
    if (gid < 512) {
        float acc = fus_b[gid];
        for (int j = 0; j < 256; ++j)
            acc += gin_b2[j] * fus_W[(size_t)(256 + j) * 512 + gid];
        bias_comb[gid] = acc;
    }
    const int stride = 256 * 256;
    const u32x4 zv = {0u, 0u, 0u, 0u};
    for (int i = gid; i < cnt4; i += stride) cnt[i] = zv;
    for (int i = gid; i < bm4; i += stride) bm[i] = zv;
}

// ---------------------------------------------------------------------------
// CSR build, 2 edges/thread (two independent atomic chains in flight)
// ---------------------------------------------------------------------------
__global__ __launch_bounds__(256) void build_hist(
    const int* __restrict__ src, const int* __restrict__ dst, int E, int N,
    int* __restrict__ cnt_dst, int* __restrict__ cnt_src,
    unsigned int* __restrict__ bitmap, unsigned char* __restrict__ flags)
{
    const int e0 = blockIdx.x * 512 + threadIdx.x;
    const int e1 = e0 + 256;
#pragma unroll
    for (int u = 0; u < 2; ++u) {
        const int e = u ? e1 : e0;
        if (e >= E) continue;
        int s = src[e], d = dst[e];
        atomicAdd(&cnt_dst[d], 1);
        unsigned int key  = (unsigned int)s * (unsigned int)N + (unsigned int)d;
        unsigned int word = key >> 5;
        unsigned int bit  = 1u << (key & 31u);
        unsigned int old  = atomicOr(&bitmap[word], bit);
        int own = (old & bit) == 0u;
        flags[e] = (unsigned char)own;
        if (own) atomicAdd(&cnt_src[s], 1);
    }
}

// scan; dst direction reserves slot 0 per segment for the self-loop and
// writes csr_src[off[d]] = d directly.
__global__ __launch_bounds__(1024) void scan_both(
    const int* __restrict__ cnt_dst, int* __restrict__ off_dst, int* __restrict__ cur_dst,
    const int* __restrict__ cnt_src, int* __restrict__ off_src, int* __restrict__ cur_src,
    int* __restrict__ csr_self)
{
    const int self = (blockIdx.x == 0);
    const int* cnt = self ? cnt_dst : cnt_src;
    int* off = self ? off_dst : off_src;
    int* cur = self ? cur_dst : cur_src;
    __shared__ int lds[1024];
    const int t = threadIdx.x;
    const int base = t * 8;
    int v[8]; int s = 0;
#pragma unroll
    for (int j = 0; j < 8; ++j) { v[j] = cnt[base + j] + self; s += v[j]; }
    lds[t] = s;
    __syncthreads();
    int mine = s;
    for (int o = 1; o < 1024; o <<= 1) {
        int add = (t >= o) ? lds[t - o] : 0;
        __syncthreads();
        lds[t] += add;
        __syncthreads();
    }
    int run = lds[t] - mine;
#pragma unroll
    for (int j = 0; j < 8; ++j) {
        off[base + j] = run;
        cur[base + j] = run + self;
        if (self) csr_self[run] = base + j;
        run += v[j];
    }
    if (t == 1023) off[8192] = run;
}

// ---------------------------------------------------------------------------
// Heterogeneous: scatter (2 edges/thread) | xlry GEMM (1536) | Wcomb (32)
// ---------------------------------------------------------------------------
__global__ __launch_bounds__(256) void scatter_gemms(
    const int* __restrict__ src, const int* __restrict__ dst, int E,
    int* __restrict__ cur_dst, int* __restrict__ cur_src,
    const unsigned char* __restrict__ flags,
    int* __restrict__ csr_src, int* __restrict__ csr_gin,
    const bf16* __restrict__ xb, const bf16* __restrict__ Wlrw_t,
    bf16* __restrict__ xlry,
    const bf16* __restrict__ Wfbot_t, const bf16* __restrict__ W2b,
    bf16* __restrict__ Wfused_t)
{
    __shared__ bf16 As[64 * 64];
    __shared__ bf16 Bs[64 * 64];
    const int nsc = (E + 511) >> 9;
    int bid = blockIdx.x;
    if (bid < nsc) {
        const int e0 = bid * 512 + threadIdx.x;
        const int e1 = e0 + 256;
        // load both edges first; two atomic chains overlap
        int s0 = 0, d0 = 0, s1 = 0, d1 = 0, f0 = 0, f1 = 0;
        const bool v0 = e0 < E, v1 = e1 < E;
        if (v0) { s0 = src[e0]; d0 = dst[e0]; f0 = flags[e0]; }
        if (v1) { s1 = src[e1]; d1 = dst[e1]; f1 = flags[e1]; }
        int p0 = v0 ? atomicAdd(&cur_dst[d0], 1) : 0;
        int p1 = v1 ? atomicAdd(&cur_dst[d1], 1) : 0;
        if (v0) csr_src[p0] = s0;
        if (v1) csr_src[p1] = s1;
        int q0 = (v0 && f0) ? atomicAdd(&cur_src[s0], 1) : 0;
        int q1 = (v1 && f1) ? atomicAdd(&cur_src[s1], 1) : 0;
        if (v0 && f0) csr_gin[q0] = d0;
        if (v1 && f1) csr_gin[q1] = d1;
        return;
    }
    bid -= nsc;
    if (bid < 1536) {
        // xlry = xb @ [W_l|W_r|W1]: M=8192, N=768, K=256; grid 12 x 128
        gemm64_body(xb, Wlrw_t, nullptr, xlry, 256, XLRW, 0,
                    bid % 12, bid / 12, 0, 1, As, Bs);
        return;
    }
    bid -= 1536;
    // Wfused bottom = Wcomb^T: grid 4x8
    gemm64_body(Wfbot_t, W2b, nullptr, Wfused_t, 256, HIDC, 256,
                bid & 3, bid >> 2, 0, 1, As, Bs);
}

// ---------------------------------------------------------------------------
// Merged GAT (blocks 0..N-1) + GIN aggregate (blocks N..2N-1).
// GAT: single-pass online softmax, 2-chunk software pipeline.
// GIN: aggregates y = x@W1, writes relu(. + b1) into cat[:,256:512].
// ---------------------------------------------------------------------------
__global__ __launch_bounds__(256, 8) void gatgin(
    const bf16* __restrict__ xlry, const int* __restrict__ csr_src,
    const int* __restrict__ off_dst, const float* __restrict__ att,
    const float* __restrict__ b_gat, bf16* __restrict__ cat,
    const int* __restrict__ csr_gin, const int* __restrict__ off_src,
    const float* __restrict__ gin_b1, int N)
{
    __shared__ float red[8 * 256];
    __shared__ float mslot[8][4];
    __shared__ float dslot[8][4];
    const int t = threadIdx.x;
    const int e8 = t >> 5, g = t & 31;

    if (blockIdx.x >= N) {
        // ---------------- GIN aggregate over y (cols 512..767), unroll x2 --
        const int i = blockIdx.x - N;
        const int beg = off_src[i], end = off_src[i + 1];
        const bf16* ybase = xlry + 512 + g * 8;
        float a0 = 0, a1 = 0, a2 = 0, a3 = 0, a4 = 0, a5 = 0, a6 = 0, a7 = 0;
        if (e8 == 0) {
            bf16x8 xv = *(const bf16x8*)(ybase + (size_t)i * XLRW);
            a0 = (float)xv[0]; a1 = (float)xv[1]; a2 = (float)xv[2]; a3 = (float)xv[3];
            a4 = (float)xv[4]; a5 = (float)xv[5]; a6 = (float)xv[6]; a7 = (float)xv[7];
        }
        int j = beg + e8;
        for (; j + 8 < end; j += 16) {
            const int s0 = csr_gin[j];
            const int s1 = csr_gin[j + 8];
            bf16x8 v0 = *(const bf16x8*)(ybase + (size_t)s0 * XLRW);
            bf16x8 v1 = *(const bf16x8*)(ybase + (size_t)s1 * XLRW);
            a0 += (float)v0[0] + (float)v1[0]; a1 += (float)v0[1] + (float)v1[1];
            a2 += (float)v0[2] + (float)v1[2]; a3 += (float)v0[3] + (float)v1[3];
            a4 += (float)v0[4] + (float)v1[4]; a5 += (float)v0[5] + (float)v1[5];
            a6 += (float)v0[6] + (float)v1[6]; a7 += (float)v0[7] + (float)v1[7];
        }
        if (j < end) {
            const int s = csr_gin[j];
            bf16x8 v = *(const bf16x8*)(ybase + (size_t)s * XLRW);
            a0 += (float)v[0]; a1 += (float)v[1]; a2 += (float)v[2]; a3 += (float)v[3];
            a4 += (float)v[4]; a5 += (float)v[5]; a6 += (float)v[6]; a7 += (float)v[7];
        }
        f32x4 lo = {a0, a1, a2, a3}, hi = {a4, a5, a6, a7};
        *(f32x4*)&red[e8 * 256 + g * 8]     = lo;
        *(f32x4*)&red[e8 * 256 + g * 8 + 4] = hi;
        __syncthreads();
        float acc = 0.0f;
#pragma unroll
        for (int s = 0; s < 8; ++s) acc += red[s * 256 + t];
        cat[(size_t)i * HIDC + 256 + t] = (bf16)fmaxf(acc + gin_b1[t], 0.0f);
        return;
    }

    // ---------------- GATv2, single-pass online softmax, pipelined x2 ------
    const int d = blockIdx.x;
    const int beg = off_dst[d];
    const int cnt = off_dst[d + 1] - beg;   // includes self slot

    float xr8[8], at8[8];
    {
        bf16x8 xv = *(const bf16x8*)&xlry[(size_t)d * XLRW + 256 + g * 8];
#pragma unroll
        for (int f = 0; f < 8; ++f) xr8[f] = (float)xv[f];
        float4 q0 = *(const float4*)&att[g * 8];
        float4 q1 = *(const float4*)&att[g * 8 + 4];
        at8[0] = q0.x; at8[1] = q0.y; at8[2] = q0.z; at8[3] = q0.w;
        at8[4] = q1.x; at8[5] = q1.y; at8[6] = q1.z; at8[7] = q1.w;
    }

    const bf16* base = xlry + g * 8;
    float m = -1e30f, den = 0.0f;
    float a[8];
#pragma unroll
    for (int f = 0; f < 8; ++f) a[f] = 0.0f;

    int jj = e8;
    for (; jj + 8 < cnt; jj += 16) {
        const int s0 = csr_src[beg + jj];
        const int s1 = csr_src[beg + jj + 8];
        bf16x8 v0 = *(const bf16x8*)(base + (size_t)s0 * XLRW);
        bf16x8 v1 = *(const bf16x8*)(base + (size_t)s1 * XLRW);
        float vf0[8], vf1[8];
        float p0 = 0.0f, p1 = 0.0f;
#pragma unroll
        for (int f = 0; f < 8; ++f) {
            vf0[f] = (float)v0[f];
            vf1[f] = (float)v1[f];
            p0 += lrelu02(vf0[f] + xr8[f]) * at8[f];
            p1 += lrelu02(vf1[f] + xr8[f]) * at8[f];
        }
        p0 += __shfl_xor(p0, 1); p1 += __shfl_xor(p1, 1);
        p0 += __shfl_xor(p0, 2); p1 += __shfl_xor(p1, 2);
        p0 += __shfl_xor(p0, 4); p1 += __shfl_xor(p1, 4);
        if (p0 > m) {
            const float r = __expf(m - p0);
            den *= r;
#pragma unroll
            for (int f = 0; f < 8; ++f) a[f] *= r;
            m = p0;
        }
        {
            const float w = __expf(p0 - m);
            den += w;
#pragma unroll
            for (int f = 0; f < 8; ++f) a[f] = fmaf(w, vf0[f], a[f]);
        }
        if (p1 > m) {
            const float r = __expf(m - p1);
            den *= r;
#pragma unroll
            for (int f = 0; f < 8; ++f) a[f] *= r;
            m = p1;
        }
        {
            const float w = __expf(p1 - m);
            den += w;
#pragma unroll
            for (int f = 0; f < 8; ++f) a[f] = fmaf(w, vf1[f], a[f]);
        }
    }
    if (jj < cnt) {
        const int s = csr_src[beg + jj];
        bf16x8 v = *(const bf16x8*)(base + (size_t)s * XLRW);
        float vf[8];
        float p = 0.0f;
#pragma unroll
        for (int f = 0; f < 8; ++f) {
            vf[f] = (float)v[f];
            p += lrelu02(vf[f] + xr8[f]) * at8[f];
        }
        p += __shfl_xor(p, 1);
        p += __shfl_xor(p, 2);
        p += __shfl_xor(p, 4);
        if (p > m) {
            const float r = __expf(m - p);
            den *= r;
#pragma unroll
            for (int f = 0; f < 8; ++f) a[f] *= r;
            m = p;
        }
        const float w = __expf(p - m);
        den += w;
#pragma unroll
        for (int f = 0; f < 8; ++f) a[f] = fmaf(w, vf[f], a[f]);
    }

    {
        f32x4 lo = {a[0], a[1], a[2], a[3]}, hi = {a[4], a[5], a[6], a[7]};
        *(f32x4*)&red[e8 * 256 + g * 8]     = lo;
        *(f32x4*)&red[e8 * 256 + g * 8 + 4] = hi;
        if ((g & 7) == 0) { mslot[e8][g >> 3] = m; dslot[e8][g >> 3] = den; }
    }
    __syncthreads();

    const int h = t >> 6;
    float M = mslot[0][h];
#pragma unroll
    for (int s2 = 1; s2 < 8; ++s2) M = fmaxf(M, mslot[s2][h]);
    float accv = 0.0f, dd = 0.0f;
#pragma unroll
    for (int s2 = 0; s2 < 8; ++s2) {
        const float sc = __expf(mslot[s2][h] - M);   // 0 for empty slots
        accv = fmaf(sc, red[s2 * 256 + t], accv);
        dd   = fmaf(sc, dslot[s2][h], dd);
    }
    cat[(size_t)d * HIDC + t] = (bf16)(accv / dd + b_gat[t]);
}

// LayerNorm over 512 features (bf16 in, fp32 out)
__global__ __launch_bounds__(256) void layernorm512(
    const bf16* __restrict__ cbuf, const float* __restrict__ g,
    const float* __restrict__ b, float* __restrict__ out)
{
    const int r = blockIdx.x;
    const int t = threadIdx.x;
    typedef __attribute__((ext_vector_type(2))) __bf16 bf16x2;
    bf16x2 pv = *(const bf16x2*)&cbuf[(size_t)r * HIDC + t * 2];
    float v0 = (float)pv[0], v1 = (float)pv[1];
    float s = v0 + v1;
    float q = v0 * v0 + v1 * v1;
    for (int o = 1; o < 64; o <<= 1) {
        s += __shfl_xor(s, o);
        q += __shfl_xor(q, o);
    }
    __shared__ float ls[4], lq[4];
    int w = t >> 6;
    if ((t & 63) == 0) { ls[w] = s; lq[w] = q; }
    __syncthreads();
    s = ls[0] + ls[1] + ls[2] + ls[3];
    q = lq[0] + lq[1] + lq[2] + lq[3];
    float mu  = s * (1.0f / 512.0f);
    float var = q * (1.0f / 512.0f) - mu * mu;
    float rs  = rsqrtf(var + 1e-5f);
    int c0 = t * 2;
    out[(size_t)r * HIDC + c0]     = (v0 - mu) * rs * g[c0]     + b[c0];
    out[(size_t)r * HIDC + c0 + 1] = (v1 - mu) * rs * g[c0 + 1] + b[c0 + 1];
}

// ---------------------------------------------------------------------------
extern "C" void kernel_launch(void* const* d_in, const int* in_sizes, int n_in,
                              void* d_out, int out_size, void* d_ws, size_t ws_size,
                              hipStream_t stream)
{
    const float* x      = (const float*)d_in[0];
    const float* W_l    = (const float*)d_in[1];
    const float* W_r    = (const float*)d_in[2];
    const float* att    = (const float*)d_in[3];
    const float* b_gat  = (const float*)d_in[4];
    const float* gin_W1 = (const float*)d_in[5];
    const float* gin_b1 = (const float*)d_in[6];
    const float* gin_W2 = (const float*)d_in[7];
    const float* gin_b2 = (const float*)d_in[8];
    const float* fus_W  = (const float*)d_in[9];
    const float* fus_b  = (const float*)d_in[10];
    const float* ln_g   = (const float*)d_in[11];
    const float* ln_b   = (const float*)d_in[12];
    const int*   eidx   = (const int*)d_in[13];

    const int E = in_sizes[13] / 2;
    const int N = in_sizes[0] / DINC;  // 8192
    const int* src = eidx;
    const int* dst = eidx + E;

    char* ws = (char*)d_ws;
    size_t off = 0;
    auto alloc = [&](size_t bytes) -> void* {
        void* p = ws + off;
        off = (off + bytes + 255) & ~(size_t)255;
        return p;
    };
    bf16* xb       = (bf16*)alloc((size_t)N * DINC * 2);
    bf16* xlry     = (bf16*)alloc((size_t)N * XLRW * 2);
    bf16* Wlrw_t   = (bf16*)alloc((size_t)768 * 256 * 2);
    bf16* Wfused_t = (bf16*)alloc((size_t)512 * 512 * 2);
    bf16* Wfbot_t  = (bf16*)alloc((size_t)512 * 256 * 2);
    bf16* W2b      = (bf16*)alloc((size_t)256 * 256 * 2);
    bf16* cat      = (bf16*)alloc((size_t)N * HIDC * 2);
    bf16* cbuf     = (bf16*)alloc((size_t)N * HIDC * 2);
    float* bias_comb = (float*)alloc(512 * 4);
    int* cnt_dst = (int*)alloc((size_t)N * 4);   // cnt_dst+cnt_src contiguous
    int* cnt_src = (int*)alloc((size_t)N * 4);
    int* off_dst = (int*)alloc((size_t)(N + 1) * 4);
    int* cur_dst = (int*)alloc((size_t)N * 4);
    int* off_src = (int*)alloc((size_t)(N + 1) * 4);
    int* cur_src = (int*)alloc((size_t)N * 4);
    int* csr_src = (int*)alloc((size_t)(E + N) * 4);   // edges + self slots
    int* csr_gin = (int*)alloc((size_t)E * 4);
    unsigned char* flags  = (unsigned char*)alloc((size_t)E);
    unsigned int*  bitmap = (unsigned int*)alloc((size_t)N * (size_t)N / 8);

    mega_prep<<<dim3(16, 16, 8), 256, 0, stream>>>(
        W_l, W_r, gin_W1, fus_W, gin_b2, fus_b, x, gin_W2,
        Wlrw_t, Wfused_t, Wfbot_t, W2b, xb, bias_comb,
        (u32x4*)cnt_dst, (2 * N) / 4,
        (u32x4*)bitmap, (int)((size_t)N * N / 32 / 4));

    build_hist<<<(E + 511) / 512, 256, 0, stream>>>(src, dst, E, N, cnt_dst, cnt_src, bitmap, flags);
    scan_both<<<2, 1024, 0, stream>>>(cnt_dst, off_dst, cur_dst,
                                      cnt_src, off_src, cur_src, csr_src);

    const int nsc = (E + 511) / 512;
    scatter_gemms<<<nsc + 1536 + 32, 256, 0, stream>>>(
        src, dst, E, cur_dst, cur_src, flags, csr_src, csr_gin,
        xb, Wlrw_t, xlry, Wfbot_t, W2b, Wfused_t);

    gatgin<<<2 * N, 256, 0, stream>>>(xlry, csr_src, off_dst, att, b_gat, cat,
                                      csr_gin, off_src, gin_b1, N);

    // fusion: relu(cat @ Wfused + bias_comb) -> cbuf (64^2 MFMA, 1024 blocks)
    gemm64<1, 1><<<dim3(8, 128), 256, 0, stream>>>(cat, Wfused_t, bias_comb, cbuf, 512, HIDC, 0);
    layernorm512<<<N, 256, 0, stream>>>(cbuf, ln_g, ln_b, (float*)d_out);

    (void)n_in; (void)out_size; (void)ws_size;
}